// Round 15
// baseline (513.949 us; speedup 1.0000x reference)
//
#include <hip/hip_runtime.h>

typedef __attribute__((ext_vector_type(4)))  float f32x4;
typedef __attribute__((ext_vector_type(16))) float f32x16;
typedef __attribute__((ext_vector_type(8)))  short short8;
typedef __attribute__((ext_vector_type(4)))  unsigned short u16x4;
typedef __attribute__((ext_vector_type(4)))  unsigned int u32x4;
typedef __attribute__((ext_vector_type(2)))  unsigned int u32x2;

// float -> bf16, round-to-nearest-even
static __device__ __forceinline__ unsigned short f2bf(float f) {
    unsigned int u = __float_as_uint(f);
    unsigned int r = (u + 0x7FFFu + ((u >> 16) & 1u)) >> 16;
    return (unsigned short)r;
}

#if __has_builtin(__builtin_amdgcn_exp2f)
#define EXP2(x) __builtin_amdgcn_exp2f(x)
#else
#define EXP2(x) exp2f(x)
#endif

static __device__ __forceinline__ u32x2 swap32v(unsigned int a, unsigned int b) {
#if __has_builtin(__builtin_amdgcn_permlane32_swap)
    return __builtin_amdgcn_permlane32_swap(a, b, false, false);
#else
    asm("v_permlane32_swap_b32 %0, %1" : "+v"(a), "+v"(b));
    u32x2 r; r[0] = a; r[1] = b; return r;
#endif
}

// keep-live helpers (rule #17: ablation-via-skip must not DCE upstream ops)
static __device__ __forceinline__ void keep8(short8 v) {
    u32x4 u = __builtin_bit_cast(u32x4, v);
    asm volatile("" :: "v"(u[0]), "v"(u[3]));
}
static __device__ __forceinline__ void keep16(f32x16 v) {
    asm volatile("" :: "v"(v[0]), "v"(v[7]), "v"(v[15]));
}

// 32^-0.5 * log2(e)
#define SCALE2Q 0.25503487756f

// ---------------------------------------------------------------------------
__global__ void prep_w_kernel(const float* __restrict__ wqk,
                              const float* __restrict__ wv,
                              unsigned short* __restrict__ W) {
    int idx = blockIdx.x * 256 + threadIdx.x;
    int o = idx >> 8, c = idx & 255;
    float v;
    if (o < 64) { v = wqk[o * 256 + c]; if (o < 32) v *= SCALE2Q; }
    else        { v = wv[(o - 64) * 256 + c]; }
    W[idx] = f2bf(v);
}

// ---------------------------------------------------------------------------
__global__ __launch_bounds__(256) void transpose_kernel(
        const float* __restrict__ x, unsigned short* __restrict__ xT) {
    __shared__ unsigned short tile[64][66];
    int b = blockIdx.x & 7;
    int rem = blockIdx.x >> 3;
    int ct = rem >> 6, st = rem & 63;
    int s0 = st * 64, c0 = ct * 64;
    int tid = threadIdx.x;
    int ss = tid & 63, cq = tid >> 6;
#pragma unroll
    for (int p = 0; p < 16; ++p) {
        int cc = p * 4 + cq;
        float v = x[(size_t)(b * 256 + c0 + cc) * 4096 + s0 + ss];
        tile[ss][cc] = f2bf(v);
    }
    __syncthreads();
#pragma unroll
    for (int p = 0; p < 8; ++p) {
        int idx = p * 256 + tid;
        int sr = idx >> 5, jj = idx & 31;
        unsigned int val = *(const unsigned int*)&tile[sr][jj * 2];
        *(unsigned int*)(xT + (size_t)(b * 4096 + s0 + sr) * 256 + c0 + jj * 2) = val;
    }
}

// ---------------------------------------------------------------------------
__global__ __launch_bounds__(256) void proj_kernel(
        const unsigned short* __restrict__ W,    // [320][256]
        const unsigned short* __restrict__ xT,   // [8][4096][256]
        unsigned short* __restrict__ qkT,        // [8][4096][64]
        unsigned short* __restrict__ vbuf) {     // [8][256][4096]
    const int b  = blockIdx.x & 7;
    const int sb = blockIdx.x >> 3;
    const int s0 = sb * 64;
    const int tid = threadIdx.x;
    const int w = tid >> 6, l = tid & 63;
    const int lg = l >> 4, ll = l & 15;
    const size_t xbase = (size_t)b * 4096 * 256;

    f32x4 acc[5][4];
#pragma unroll
    for (int ot = 0; ot < 5; ++ot)
#pragma unroll
        for (int st = 0; st < 4; ++st) acc[ot][st] = (f32x4)0.0f;

    for (int k0 = 0; k0 < 256; k0 += 32) {
        short8 bf[4], af[5];
#pragma unroll
        for (int st = 0; st < 4; ++st)
            bf[st] = *(const short8*)(xT + xbase + (size_t)(s0 + st * 16 + ll) * 256 + k0 + lg * 8);
#pragma unroll
        for (int ot = 0; ot < 5; ++ot)
            af[ot] = *(const short8*)(W + (size_t)(80 * w + ot * 16 + ll) * 256 + k0 + lg * 8);
#pragma unroll
        for (int ot = 0; ot < 5; ++ot)
#pragma unroll
            for (int st = 0; st < 4; ++st)
                acc[ot][st] = __builtin_amdgcn_mfma_f32_16x16x32_bf16(af[ot], bf[st], acc[ot][st], 0, 0, 0);
    }
#pragma unroll
    for (int ot = 0; ot < 5; ++ot) {
        int o0 = 80 * w + ot * 16 + lg * 4;
#pragma unroll
        for (int st = 0; st < 4; ++st) {
            int s = s0 + st * 16 + ll;
            if (o0 < 64) {
                u16x4 pk;
#pragma unroll
                for (int i = 0; i < 4; ++i) pk[i] = f2bf(acc[ot][st][i]);
                *(u16x4*)(qkT + (size_t)b * 4096 * 64 + (size_t)s * 64 + o0) = pk;
            } else {
#pragma unroll
                for (int i = 0; i < 4; ++i)
                    vbuf[(size_t)b * 256 * 4096 + (size_t)(o0 - 64 + i) * 4096 + s] = f2bf(acc[ot][st][i]);
            }
        }
    }
}

// ---------------------------------------------------------------------------
__global__ __launch_bounds__(256) void repack_v_kernel(
        const unsigned short* __restrict__ vbuf,   // [8][256][4096]
        unsigned short* __restrict__ vfrag) {      // [8][8][256][64][8]
    int idx = blockIdx.x * 256 + threadIdx.x;
    int l    = idx & 63;
    int kf16 = (idx >> 6) & 255;
    int ct4  = (idx >> 14) & 7;
    int b    = idx >> 17;
    int l31 = l & 31, l5 = l >> 5;
    short8 v = *(const short8*)(vbuf + (size_t)b * 256 * 4096
                                + (size_t)(32 * ct4 + l31) * 4096
                                + 16 * kf16 + 8 * l5);
    *(short8*)(vfrag + (size_t)idx * 8) = v;
}

// ---------------------------------------------------------------------------
__global__ __launch_bounds__(256) void repack_k_kernel(
        const unsigned short* __restrict__ qkT,    // [8][4096][64]
        unsigned short* __restrict__ kfrag) {      // [8][128][2][64][8]
    int idx = blockIdx.x * 256 + threadIdx.x;
    int l  = idx & 63;
    int h  = (idx >> 6) & 1;
    int t2 = (idx >> 7) & 127;
    int b  = idx >> 14;
    int l31 = l & 31, l5 = l >> 5;
    short8 v = *(const short8*)(qkT + (size_t)b * 4096 * 64
                                + (size_t)(32 * t2 + l31) * 64
                                + 32 + 16 * h + 8 * l5);
    *(short8*)(kfrag + (size_t)idx * 8) = v;
}

// ---------------------------------------------------------------------------
// ABLATION attention (R11 structure). MODE: 0=full(real out) 1=no-QK-MFMA
// 2=no-exp/pack 3=no-PV-MFMA 4=no-rolling-reloads. Non-zero modes write a
// per-thread digest to dbg (keeps everything live, never touches out).
// ---------------------------------------------------------------------------
template <int MODE>
__global__ __launch_bounds__(512, 2) void attn_kernel(
        const unsigned short* __restrict__ qkT,   // [8][4096][64] (q|k)
        const unsigned short* __restrict__ kfrag, // [8][128][2][64][8]
        const unsigned short* __restrict__ vfrag, // [8][8][256][64][8]
        const float* __restrict__ x,              // [8][256][4096]
        const float* __restrict__ gamma,
        float* __restrict__ out,
        float* __restrict__ dbg) {
    __shared__ float lsum_lds[256];

    const int b     = blockIdx.x & 7;
    const int sb    = (blockIdx.x >> 3) & 15;
    const int chalf = blockIdx.x >> 7;
    const int s0    = sb * 256;
    const int w     = threadIdx.x >> 6;
    const int l     = threadIdx.x & 63;
    const int l5    = l >> 5, l31 = l & 31;

    const size_t qk_base = (size_t)b * 4096 * 64;
    const size_t bx_base = (size_t)b * 256 * 4096;
    const int chbase = 128 * chalf;

    const unsigned short* qrow = qkT + qk_base + (size_t)(s0 + 32 * w + l31) * 64;
    const short8 qf0 = *(const short8*)(qrow + 8 * l5);
    const short8 qf1 = *(const short8*)(qrow + 16 + 8 * l5);

    const unsigned short* kfp  = kfrag + (size_t)b * 128 * 2 * 512 + 8 * l;
    const unsigned short* vf0p = vfrag + ((size_t)(b * 8 + chalf * 4 + 0) * 256) * 512 + 8 * l;
    const unsigned short* vf1p = vfrag + ((size_t)(b * 8 + chalf * 4 + 1) * 256) * 512 + 8 * l;
    const unsigned short* vf2p = vfrag + ((size_t)(b * 8 + chalf * 4 + 2) * 256) * 512 + 8 * l;
    const unsigned short* vf3p = vfrag + ((size_t)(b * 8 + chalf * 4 + 3) * 256) * 512 + 8 * l;

    f32x16 acc0 = (f32x16)0.0f, acc1 = (f32x16)0.0f;
    f32x16 acc2 = (f32x16)0.0f, acc3 = (f32x16)0.0f;
    float psum = 0.f;
    const f32x16 z16 = (f32x16)0.0f;

    short8 kf00 = *(const short8*)(kfp + 0 * 512);
    short8 kf01 = *(const short8*)(kfp + 1 * 512);
    short8 kf10 = *(const short8*)(kfp + 2 * 512);
    short8 kf11 = *(const short8*)(kfp + 3 * 512);
    short8 vA0 = *(const short8*)(vf0p + 0 * 512);
    short8 vA1 = *(const short8*)(vf1p + 0 * 512);
    short8 vA2 = *(const short8*)(vf2p + 0 * 512);
    short8 vA3 = *(const short8*)(vf3p + 0 * 512);
    short8 vB0 = *(const short8*)(vf0p + 1 * 512);
    short8 vB1 = *(const short8*)(vf1p + 1 * 512);
    short8 vB2 = *(const short8*)(vf2p + 1 * 512);
    short8 vB3 = *(const short8*)(vf3p + 1 * 512);

#define EXPPACK(DD, PLO, PHI)                                                  \
    {                                                                          \
        float e0 = EXP2((DD)[0]),   e1 = EXP2((DD)[1]);                        \
        float e2 = EXP2((DD)[2]),   e3 = EXP2((DD)[3]);                        \
        float e4 = EXP2((DD)[4]),   e5 = EXP2((DD)[5]);                        \
        float e6 = EXP2((DD)[6]),   e7 = EXP2((DD)[7]);                        \
        float e8 = EXP2((DD)[8]),   e9 = EXP2((DD)[9]);                        \
        float e10 = EXP2((DD)[10]), e11 = EXP2((DD)[11]);                      \
        float e12 = EXP2((DD)[12]), e13 = EXP2((DD)[13]);                      \
        float e14 = EXP2((DD)[14]), e15 = EXP2((DD)[15]);                      \
        psum += (((e0 + e1) + (e2 + e3)) + ((e4 + e5) + (e6 + e7)))            \
              + (((e8 + e9) + (e10 + e11)) + ((e12 + e13) + (e14 + e15)));     \
        unsigned int c0, c1, c2, c3;                                           \
        asm("v_cvt_pk_bf16_f32 %0, %1, %2" : "=v"(c0) : "v"(e0), "v"(e1));     \
        asm("v_cvt_pk_bf16_f32 %0, %1, %2" : "=v"(c1) : "v"(e2), "v"(e3));     \
        asm("v_cvt_pk_bf16_f32 %0, %1, %2" : "=v"(c2) : "v"(e4), "v"(e5));     \
        asm("v_cvt_pk_bf16_f32 %0, %1, %2" : "=v"(c3) : "v"(e6), "v"(e7));     \
        u32x2 s0_ = swap32v(c0, c2);                                           \
        u32x2 s1_ = swap32v(c1, c3);                                           \
        u32x4 lo_; lo_[0] = s0_[0]; lo_[1] = s1_[0]; lo_[2] = s0_[1]; lo_[3] = s1_[1]; \
        PLO = __builtin_bit_cast(short8, lo_);                                 \
        unsigned int d0, d1, d2, d3;                                           \
        asm("v_cvt_pk_bf16_f32 %0, %1, %2" : "=v"(d0) : "v"(e8), "v"(e9));     \
        asm("v_cvt_pk_bf16_f32 %0, %1, %2" : "=v"(d1) : "v"(e10), "v"(e11));   \
        asm("v_cvt_pk_bf16_f32 %0, %1, %2" : "=v"(d2) : "v"(e12), "v"(e13));   \
        u32x2 s2_ = swap32v(d0, d2);                                           \
        asm("v_cvt_pk_bf16_f32 %0, %1, %2" : "=v"(d3) : "v"(e14), "v"(e15));   \
        u32x2 s3_ = swap32v(d1, d3);                                           \
        u32x4 hi_; hi_[0] = s2_[0]; hi_[1] = s3_[0]; hi_[2] = s2_[1]; hi_[3] = s3_[1]; \
        PHI = __builtin_bit_cast(short8, hi_);                                 \
    }

#define PV4(PA, V0, V1, V2, V3)                                                \
    acc0 = __builtin_amdgcn_mfma_f32_32x32x16_bf16(PA, V0, acc0, 0, 0, 0);     \
    acc1 = __builtin_amdgcn_mfma_f32_32x32x16_bf16(PA, V1, acc1, 0, 0, 0);     \
    acc2 = __builtin_amdgcn_mfma_f32_32x32x16_bf16(PA, V2, acc2, 0, 0, 0);     \
    acc3 = __builtin_amdgcn_mfma_f32_32x32x16_bf16(PA, V3, acc3, 0, 0, 0);

    for (int t = 0; t < 64; ++t) {
        const int tn = (t + 1) & 63;

        // ---- QK ----
        f32x16 dd0, dd1;
        if constexpr (MODE != 1) {
            dd0 = __builtin_amdgcn_mfma_f32_32x32x16_bf16(kf00, qf0, z16, 0, 0, 0);
            dd0 = __builtin_amdgcn_mfma_f32_32x32x16_bf16(kf01, qf1, dd0, 0, 0, 0);
            dd1 = __builtin_amdgcn_mfma_f32_32x32x16_bf16(kf10, qf0, z16, 0, 0, 0);
            dd1 = __builtin_amdgcn_mfma_f32_32x32x16_bf16(kf11, qf1, dd1, 0, 0, 0);
        } else {
            dd0 = z16; dd1 = z16;
            keep8(kf00); keep8(kf01); keep8(kf10); keep8(kf11);
        }
        if constexpr (MODE != 4) {
            kf00 = *(const short8*)(kfp + (size_t)(4 * tn + 0) * 512);
            kf01 = *(const short8*)(kfp + (size_t)(4 * tn + 1) * 512);
            kf10 = *(const short8*)(kfp + (size_t)(4 * tn + 2) * 512);
            kf11 = *(const short8*)(kfp + (size_t)(4 * tn + 3) * 512);
        }

        // ---- softmax numerator tile 0 ----
        short8 pa0, pa1;
        if constexpr (MODE != 2) { EXPPACK(dd0, pa0, pa1) }
        else { keep16(dd0); pa0 = kf00; pa1 = kf01; psum += 1.0f; }

        if constexpr (MODE != 3) { PV4(pa0, vA0, vA1, vA2, vA3) }
        else { keep8(pa0); keep8(vA0); keep8(vA1); keep8(vA2); keep8(vA3); }
        if constexpr (MODE != 4) {
            vA0 = *(const short8*)(vf0p + (size_t)(4 * t + 2) * 512);
            vA1 = *(const short8*)(vf1p + (size_t)(4 * t + 2) * 512);
            vA2 = *(const short8*)(vf2p + (size_t)(4 * t + 2) * 512);
            vA3 = *(const short8*)(vf3p + (size_t)(4 * t + 2) * 512);
        }
        if constexpr (MODE != 3) { PV4(pa1, vB0, vB1, vB2, vB3) }
        else { keep8(pa1); keep8(vB0); keep8(vB1); keep8(vB2); keep8(vB3); }
        if constexpr (MODE != 4) {
            vB0 = *(const short8*)(vf0p + (size_t)(4 * t + 3) * 512);
            vB1 = *(const short8*)(vf1p + (size_t)(4 * t + 3) * 512);
            vB2 = *(const short8*)(vf2p + (size_t)(4 * t + 3) * 512);
            vB3 = *(const short8*)(vf3p + (size_t)(4 * t + 3) * 512);
        }

        // ---- softmax numerator tile 1 ----
        short8 pa2, pa3;
        if constexpr (MODE != 2) { EXPPACK(dd1, pa2, pa3) }
        else { keep16(dd1); pa2 = kf10; pa3 = kf11; }

        if constexpr (MODE != 3) { PV4(pa2, vA0, vA1, vA2, vA3) }
        else { keep8(pa2); keep8(vA0); keep8(vA1); keep8(vA2); keep8(vA3); }
        if constexpr (MODE != 4) {
            vA0 = *(const short8*)(vf0p + (size_t)(4 * tn + 0) * 512);
            vA1 = *(const short8*)(vf1p + (size_t)(4 * tn + 0) * 512);
            vA2 = *(const short8*)(vf2p + (size_t)(4 * tn + 0) * 512);
            vA3 = *(const short8*)(vf3p + (size_t)(4 * tn + 0) * 512);
        }
        if constexpr (MODE != 3) { PV4(pa3, vB0, vB1, vB2, vB3) }
        else { keep8(pa3); keep8(vB0); keep8(vB1); keep8(vB2); keep8(vB3); }
        if constexpr (MODE != 4) {
            vB0 = *(const short8*)(vf0p + (size_t)(4 * tn + 1) * 512);
            vB1 = *(const short8*)(vf1p + (size_t)(4 * tn + 1) * 512);
            vB2 = *(const short8*)(vf2p + (size_t)(4 * tn + 1) * 512);
            vB3 = *(const short8*)(vf3p + (size_t)(4 * tn + 1) * 512);
        }
    }
#undef EXPPACK
#undef PV4

    if constexpr (MODE == 0) {
        psum += __shfl_xor(psum, 32);
        if (l5 == 0) lsum_lds[32 * w + l31] = psum;
        __syncthreads();

        const float g = gamma[0];
#pragma unroll
        for (int rq = 0; rq < 4; ++rq) {
            f32x4 ls = *(const f32x4*)&lsum_lds[32 * w + 8 * rq + 4 * l5];
            f32x4 gi;
#pragma unroll
            for (int m = 0; m < 4; ++m) gi[m] = g / ls[m];
            const int srow = s0 + 32 * w + 8 * rq + 4 * l5;
#define STORE_CT(ACC, CT)                                                      \
            {                                                                  \
                size_t off = bx_base + (size_t)(chbase + 32 * (CT) + l31) * 4096 + srow; \
                f32x4 xv = *(const f32x4*)(x + off);                           \
                f32x4 o;                                                       \
                o[0] = gi[0] * (ACC)[4 * rq + 0] + xv[0];                      \
                o[1] = gi[1] * (ACC)[4 * rq + 1] + xv[1];                      \
                o[2] = gi[2] * (ACC)[4 * rq + 2] + xv[2];                      \
                o[3] = gi[3] * (ACC)[4 * rq + 3] + xv[3];                      \
                *(f32x4*)(out + off) = o;                                      \
            }
            STORE_CT(acc0, 0)
            STORE_CT(acc1, 1)
            STORE_CT(acc2, 2)
            STORE_CT(acc3, 3)
#undef STORE_CT
        }
    } else {
        // digest keeps acc/psum (and thus all upstream work) observable
        float dg = psum + acc0[0] + acc0[15] + acc1[0] + acc1[7]
                        + acc2[0] + acc2[11] + acc3[0] + acc3[3]
                        + (float)gamma[0];
        dbg[(size_t)blockIdx.x * 512 + threadIdx.x] = dg;
    }
}

// ---------------------------------------------------------------------------
extern "C" void kernel_launch(void* const* d_in, const int* in_sizes, int n_in,
                              void* d_out, int out_size, void* d_ws, size_t ws_size,
                              hipStream_t stream) {
    const float* x     = (const float*)d_in[0];
    const float* wqk   = (const float*)d_in[1];
    const float* wv    = (const float*)d_in[2];
    const float* gamma = (const float*)d_in[3];
    float* out = (float*)d_out;

    char* ws = (char*)d_ws;
    unsigned short* W     = (unsigned short*)(ws);                      // 160 KiB
    unsigned short* qkT   = (unsigned short*)(ws + 163840);             // 4 MiB
    unsigned short* xT    = (unsigned short*)(ws + 4358144);            // 16 MiB (-> vfrag)
    unsigned short* vbuf  = (unsigned short*)(ws + 21135360);           // 16 MiB
    unsigned short* kfrag = (unsigned short*)(ws + 37912576);           // 2 MiB
    float*          dbg   = (float*)(ws + 40009728);                    // 512 KiB
    unsigned short* vfrag = xT;

    hipLaunchKernelGGL(prep_w_kernel,    dim3(320),  dim3(256), 0, stream, wqk, wv, W);
    hipLaunchKernelGGL(transpose_kernel, dim3(2048), dim3(256), 0, stream, x, xT);
    hipLaunchKernelGGL(proj_kernel,      dim3(512),  dim3(256), 0, stream, W, xT, qkT, vbuf);
    hipLaunchKernelGGL(repack_v_kernel,  dim3(4096), dim3(256), 0, stream, vbuf, vfrag);
    hipLaunchKernelGGL(repack_k_kernel,  dim3(512),  dim3(256), 0, stream, qkT, kfrag);

    // ablation variants (scratch digests), then the real kernel
    hipLaunchKernelGGL((attn_kernel<1>), dim3(256), dim3(512), 0, stream, qkT, kfrag, vfrag, x, gamma, out, dbg);
    hipLaunchKernelGGL((attn_kernel<2>), dim3(256), dim3(512), 0, stream, qkT, kfrag, vfrag, x, gamma, out, dbg);
    hipLaunchKernelGGL((attn_kernel<3>), dim3(256), dim3(512), 0, stream, qkT, kfrag, vfrag, x, gamma, out, dbg);
    hipLaunchKernelGGL((attn_kernel<4>), dim3(256), dim3(512), 0, stream, qkT, kfrag, vfrag, x, gamma, out, dbg);
    hipLaunchKernelGGL((attn_kernel<0>), dim3(256), dim3(512), 0, stream, qkT, kfrag, vfrag, x, gamma, out, dbg);
}

// Round 16
// 146.062 us; speedup vs baseline: 3.5187x; 3.5187x over previous
//
#include <hip/hip_runtime.h>

typedef __attribute__((ext_vector_type(4)))  float f32x4;
typedef __attribute__((ext_vector_type(16))) float f32x16;
typedef __attribute__((ext_vector_type(8)))  short short8;
typedef __attribute__((ext_vector_type(4)))  unsigned short u16x4;
typedef __attribute__((ext_vector_type(4)))  unsigned int u32x4;
typedef __attribute__((ext_vector_type(2)))  unsigned int u32x2;

// float -> bf16, round-to-nearest-even
static __device__ __forceinline__ unsigned short f2bf(float f) {
    unsigned int u = __float_as_uint(f);
    unsigned int r = (u + 0x7FFFu + ((u >> 16) & 1u)) >> 16;
    return (unsigned short)r;
}

#if __has_builtin(__builtin_amdgcn_exp2f)
#define EXP2(x) __builtin_amdgcn_exp2f(x)
#else
#define EXP2(x) exp2f(x)
#endif

static __device__ __forceinline__ u32x2 swap32v(unsigned int a, unsigned int b) {
#if __has_builtin(__builtin_amdgcn_permlane32_swap)
    return __builtin_amdgcn_permlane32_swap(a, b, false, false);
#else
    asm("v_permlane32_swap_b32 %0, %1" : "+v"(a), "+v"(b));
    u32x2 r; r[0] = a; r[1] = b; return r;
#endif
}

// lgkm-drain + raw barrier (vmcnt NOT drained: K/V prefetches stay in flight)
static __device__ __forceinline__ void block_sync_lds() {
    asm volatile("s_waitcnt lgkmcnt(0)" ::: "memory");
    __builtin_amdgcn_s_barrier();
    asm volatile("" ::: "memory");
}

// 32^-0.5 * log2(e)
#define SCALE2Q 0.25503487756f

// ---------------------------------------------------------------------------
__global__ void prep_w_kernel(const float* __restrict__ wqk,
                              const float* __restrict__ wv,
                              unsigned short* __restrict__ W) {
    int idx = blockIdx.x * 256 + threadIdx.x;
    int o = idx >> 8, c = idx & 255;
    float v;
    if (o < 64) { v = wqk[o * 256 + c]; if (o < 32) v *= SCALE2Q; }
    else        { v = wv[(o - 64) * 256 + c]; }
    W[idx] = f2bf(v);
}

// ---------------------------------------------------------------------------
__global__ __launch_bounds__(256) void transpose_kernel(
        const float* __restrict__ x, unsigned short* __restrict__ xT) {
    __shared__ unsigned short tile[64][66];
    int b = blockIdx.x & 7;
    int rem = blockIdx.x >> 3;
    int ct = rem >> 6, st = rem & 63;
    int s0 = st * 64, c0 = ct * 64;
    int tid = threadIdx.x;
    int ss = tid & 63, cq = tid >> 6;
#pragma unroll
    for (int p = 0; p < 16; ++p) {
        int cc = p * 4 + cq;
        float v = x[(size_t)(b * 256 + c0 + cc) * 4096 + s0 + ss];
        tile[ss][cc] = f2bf(v);
    }
    __syncthreads();
#pragma unroll
    for (int p = 0; p < 8; ++p) {
        int idx = p * 256 + tid;
        int sr = idx >> 5, jj = idx & 31;
        unsigned int val = *(const unsigned int*)&tile[sr][jj * 2];
        *(unsigned int*)(xT + (size_t)(b * 4096 + s0 + sr) * 256 + c0 + jj * 2) = val;
    }
}

// ---------------------------------------------------------------------------
__global__ __launch_bounds__(256) void proj_kernel(
        const unsigned short* __restrict__ W,    // [320][256]
        const unsigned short* __restrict__ xT,   // [8][4096][256]
        unsigned short* __restrict__ qkT,        // [8][4096][64]
        unsigned short* __restrict__ vbuf) {     // [8][256][4096]
    const int b  = blockIdx.x & 7;
    const int sb = blockIdx.x >> 3;
    const int s0 = sb * 64;
    const int tid = threadIdx.x;
    const int w = tid >> 6, l = tid & 63;
    const int lg = l >> 4, ll = l & 15;
    const size_t xbase = (size_t)b * 4096 * 256;

    f32x4 acc[5][4];
#pragma unroll
    for (int ot = 0; ot < 5; ++ot)
#pragma unroll
        for (int st = 0; st < 4; ++st) acc[ot][st] = (f32x4)0.0f;

    for (int k0 = 0; k0 < 256; k0 += 32) {
        short8 bf[4], af[5];
#pragma unroll
        for (int st = 0; st < 4; ++st)
            bf[st] = *(const short8*)(xT + xbase + (size_t)(s0 + st * 16 + ll) * 256 + k0 + lg * 8);
#pragma unroll
        for (int ot = 0; ot < 5; ++ot)
            af[ot] = *(const short8*)(W + (size_t)(80 * w + ot * 16 + ll) * 256 + k0 + lg * 8);
#pragma unroll
        for (int ot = 0; ot < 5; ++ot)
#pragma unroll
            for (int st = 0; st < 4; ++st)
                acc[ot][st] = __builtin_amdgcn_mfma_f32_16x16x32_bf16(af[ot], bf[st], acc[ot][st], 0, 0, 0);
    }
#pragma unroll
    for (int ot = 0; ot < 5; ++ot) {
        int o0 = 80 * w + ot * 16 + lg * 4;
#pragma unroll
        for (int st = 0; st < 4; ++st) {
            int s = s0 + st * 16 + ll;
            if (o0 < 64) {
                u16x4 pk;
#pragma unroll
                for (int i = 0; i < 4; ++i) pk[i] = f2bf(acc[ot][st][i]);
                *(u16x4*)(qkT + (size_t)b * 4096 * 64 + (size_t)s * 64 + o0) = pk;
            } else {
#pragma unroll
                for (int i = 0; i < 4; ++i)
                    vbuf[(size_t)b * 256 * 4096 + (size_t)(o0 - 64 + i) * 4096 + s] = f2bf(acc[ot][st][i]);
            }
        }
    }
}

// ---------------------------------------------------------------------------
__global__ __launch_bounds__(256) void repack_v_kernel(
        const unsigned short* __restrict__ vbuf,   // [8][256][4096]
        unsigned short* __restrict__ vfrag) {      // [8][8][256][64][8]
    int idx = blockIdx.x * 256 + threadIdx.x;
    int l    = idx & 63;
    int kf16 = (idx >> 6) & 255;
    int ct4  = (idx >> 14) & 7;
    int b    = idx >> 17;
    int l31 = l & 31, l5 = l >> 5;
    short8 v = *(const short8*)(vbuf + (size_t)b * 256 * 4096
                                + (size_t)(32 * ct4 + l31) * 4096
                                + 16 * kf16 + 8 * l5);
    *(short8*)(vfrag + (size_t)idx * 8) = v;
}

// ---------------------------------------------------------------------------
__global__ __launch_bounds__(256) void repack_k_kernel(
        const unsigned short* __restrict__ qkT,    // [8][4096][64]
        unsigned short* __restrict__ kfrag) {      // [8][128][2][64][8]
    int idx = blockIdx.x * 256 + threadIdx.x;
    int l  = idx & 63;
    int h  = (idx >> 6) & 1;
    int t2 = (idx >> 7) & 127;
    int b  = idx >> 14;
    int l31 = l & 31, l5 = l >> 5;
    short8 v = *(const short8*)(qkT + (size_t)b * 4096 * 64
                                + (size_t)(32 * t2 + l31) * 64
                                + 32 + 16 * h + 8 * l5);
    *(short8*)(kfrag + (size_t)idx * 8) = v;
}

// ---------------------------------------------------------------------------
// Kernel 4: attention, producer/consumer wave split + coalesced frag paths.
// grid 256 = 8 b x 32 q-tiles(128); block 768 = 12 waves, 1 block/CU.
// Waves 0-3 (producers, 32 q each): coalesced kfrag loads -> swapped QK
// (mfma_32x32x16) -> exp2 -> cvt_pk+permlane (in-register softmax) ->
// 4x ds_write_b128 of ready PV A-frags into double-buffered p_lds.
// Waves 4-11 (consumers, 32 ch each): 16x ds_read_b128 (conflict-free) +
// 16 PV MFMA + 4 rolling coalesced vfrag loads per tile.
// One lgkm-only barrier per tile; 1-tile producer/consumer skew.
// Roles in disjoint loops (no register-pressure union). QK computed ONCE.
// ---------------------------------------------------------------------------
__global__ __launch_bounds__(768, 3) void attn_kernel(
        const unsigned short* __restrict__ qkT,   // [8][4096][64] (q|k)
        const unsigned short* __restrict__ kfrag, // [8][128][2][64][8]
        const unsigned short* __restrict__ vfrag, // [8][8][256][64][8]
        const float* __restrict__ x,              // [8][256][4096]
        const float* __restrict__ gamma,
        float* __restrict__ out) {
    __shared__ unsigned short p_lds[2][4][4][64][8];  // 32 KiB [buf][qb][ks][lane][8]
    __shared__ float lsum_lds[128];

    const int b   = blockIdx.x & 7;          // batch == XCD (L2 pinning)
    const int sb  = blockIdx.x >> 3;         // 0..31
    const int s0  = sb * 128;
    const int w   = threadIdx.x >> 6;        // 0..11
    const int l   = threadIdx.x & 63;
    const int l5  = l >> 5, l31 = l & 31;

    const size_t qk_base = (size_t)b * 4096 * 64;
    const size_t bx_base = (size_t)b * 256 * 4096;

    if (w < 4) {
        // ================= PRODUCER: q-rows [s0+32w, +32) ===================
        const unsigned short* qrow = qkT + qk_base + (size_t)(s0 + 32 * w + l31) * 64;
        const short8 qf0 = *(const short8*)(qrow + 8 * l5);
        const short8 qf1 = *(const short8*)(qrow + 16 + 8 * l5);
        const unsigned short* kfp = kfrag + (size_t)b * 128 * 2 * 512 + 8 * l;
        const f32x16 z16 = (f32x16)0.0f;
        float psum = 0.f;

        short8 kf00 = *(const short8*)(kfp + 0 * 512);
        short8 kf01 = *(const short8*)(kfp + 1 * 512);
        short8 kf10 = *(const short8*)(kfp + 2 * 512);
        short8 kf11 = *(const short8*)(kfp + 3 * 512);

#define EXPPACK(DD, PLO, PHI)                                                  \
    {                                                                          \
        float e0 = EXP2((DD)[0]),   e1 = EXP2((DD)[1]);                        \
        float e2 = EXP2((DD)[2]),   e3 = EXP2((DD)[3]);                        \
        float e4 = EXP2((DD)[4]),   e5 = EXP2((DD)[5]);                        \
        float e6 = EXP2((DD)[6]),   e7 = EXP2((DD)[7]);                        \
        float e8 = EXP2((DD)[8]),   e9 = EXP2((DD)[9]);                        \
        float e10 = EXP2((DD)[10]), e11 = EXP2((DD)[11]);                      \
        float e12 = EXP2((DD)[12]), e13 = EXP2((DD)[13]);                      \
        float e14 = EXP2((DD)[14]), e15 = EXP2((DD)[15]);                      \
        psum += (((e0 + e1) + (e2 + e3)) + ((e4 + e5) + (e6 + e7)))            \
              + (((e8 + e9) + (e10 + e11)) + ((e12 + e13) + (e14 + e15)));     \
        unsigned int c0, c1, c2, c3;                                           \
        asm("v_cvt_pk_bf16_f32 %0, %1, %2" : "=v"(c0) : "v"(e0), "v"(e1));     \
        asm("v_cvt_pk_bf16_f32 %0, %1, %2" : "=v"(c1) : "v"(e2), "v"(e3));     \
        asm("v_cvt_pk_bf16_f32 %0, %1, %2" : "=v"(c2) : "v"(e4), "v"(e5));     \
        asm("v_cvt_pk_bf16_f32 %0, %1, %2" : "=v"(c3) : "v"(e6), "v"(e7));     \
        u32x2 s0_ = swap32v(c0, c2);                                           \
        u32x2 s1_ = swap32v(c1, c3);                                           \
        u32x4 lo_; lo_[0] = s0_[0]; lo_[1] = s1_[0]; lo_[2] = s0_[1]; lo_[3] = s1_[1]; \
        PLO = __builtin_bit_cast(short8, lo_);                                 \
        unsigned int d0, d1, d2, d3;                                           \
        asm("v_cvt_pk_bf16_f32 %0, %1, %2" : "=v"(d0) : "v"(e8), "v"(e9));     \
        asm("v_cvt_pk_bf16_f32 %0, %1, %2" : "=v"(d1) : "v"(e10), "v"(e11));   \
        asm("v_cvt_pk_bf16_f32 %0, %1, %2" : "=v"(d2) : "v"(e12), "v"(e13));   \
        u32x2 s2_ = swap32v(d0, d2);                                           \
        asm("v_cvt_pk_bf16_f32 %0, %1, %2" : "=v"(d3) : "v"(e14), "v"(e15));   \
        u32x2 s3_ = swap32v(d1, d3);                                           \
        u32x4 hi_; hi_[0] = s2_[0]; hi_[1] = s3_[0]; hi_[2] = s2_[1]; hi_[3] = s3_[1]; \
        PHI = __builtin_bit_cast(short8, hi_);                                 \
    }

#define PRODUCE(T)                                                             \
    {                                                                          \
        const int tn_ = ((T) + 1) & 63;                                        \
        const int pb_ = (T) & 1;                                               \
        f32x16 dd0 = __builtin_amdgcn_mfma_f32_32x32x16_bf16(kf00, qf0, z16, 0, 0, 0); \
        dd0 = __builtin_amdgcn_mfma_f32_32x32x16_bf16(kf01, qf1, dd0, 0, 0, 0);\
        f32x16 dd1 = __builtin_amdgcn_mfma_f32_32x32x16_bf16(kf10, qf0, z16, 0, 0, 0); \
        dd1 = __builtin_amdgcn_mfma_f32_32x32x16_bf16(kf11, qf1, dd1, 0, 0, 0);\
        kf00 = *(const short8*)(kfp + (size_t)(4 * tn_ + 0) * 512);            \
        kf01 = *(const short8*)(kfp + (size_t)(4 * tn_ + 1) * 512);            \
        kf10 = *(const short8*)(kfp + (size_t)(4 * tn_ + 2) * 512);            \
        kf11 = *(const short8*)(kfp + (size_t)(4 * tn_ + 3) * 512);            \
        short8 pa0, pa1, pa2, pa3;                                             \
        EXPPACK(dd0, pa0, pa1)                                                 \
        EXPPACK(dd1, pa2, pa3)                                                 \
        *(short8*)&p_lds[pb_][w][0][l][0] = pa0;                               \
        *(short8*)&p_lds[pb_][w][1][l][0] = pa1;                               \
        *(short8*)&p_lds[pb_][w][2][l][0] = pa2;                               \
        *(short8*)&p_lds[pb_][w][3][l][0] = pa3;                               \
    }

        PRODUCE(0)
        for (int t = 1; t < 64; ++t) {
            block_sync_lds();
            PRODUCE(t)
        }
        block_sync_lds();    // sync #64: consumer starts tile 63
#undef PRODUCE
#undef EXPPACK

        psum += __shfl_xor(psum, 32);
        if (l5 == 0) lsum_lds[32 * w + l31] = psum;
        __syncthreads();
    } else {
        // ================= CONSUMER: channels [32(w-4), +32) ================
        const int cw = w - 4;                 // 0..7
        const int ch = 32 * cw + l31;
        const unsigned short* vfp = vfrag + ((size_t)(b * 8 + cw) * 256) * 512 + 8 * l;

        f32x16 acc0 = (f32x16)0.0f, acc1 = (f32x16)0.0f;
        f32x16 acc2 = (f32x16)0.0f, acc3 = (f32x16)0.0f;
        short8 vf0 = *(const short8*)(vfp + 0 * 512);
        short8 vf1 = *(const short8*)(vfp + 1 * 512);
        short8 vf2 = *(const short8*)(vfp + 2 * 512);
        short8 vf3 = *(const short8*)(vfp + 3 * 512);

#define CKS(KS, VF)                                                            \
        {                                                                      \
            short8 p0 = *(const short8*)&p_lds[pb][0][KS][l][0];               \
            short8 p1 = *(const short8*)&p_lds[pb][1][KS][l][0];               \
            short8 p2 = *(const short8*)&p_lds[pb][2][KS][l][0];               \
            short8 p3 = *(const short8*)&p_lds[pb][3][KS][l][0];               \
            acc0 = __builtin_amdgcn_mfma_f32_32x32x16_bf16(p0, VF, acc0, 0, 0, 0); \
            acc1 = __builtin_amdgcn_mfma_f32_32x32x16_bf16(p1, VF, acc1, 0, 0, 0); \
            acc2 = __builtin_amdgcn_mfma_f32_32x32x16_bf16(p2, VF, acc2, 0, 0, 0); \
            acc3 = __builtin_amdgcn_mfma_f32_32x32x16_bf16(p3, VF, acc3, 0, 0, 0); \
            VF = *(const short8*)(vfp + (size_t)(4 * tn + (KS)) * 512);        \
        }

        for (int t = 0; t < 64; ++t) {
            block_sync_lds();
            const int pb = t & 1;
            const int tn = (t + 1) & 63;
            CKS(0, vf0)
            CKS(1, vf1)
            CKS(2, vf2)
            CKS(3, vf3)
        }
#undef CKS
        __syncthreads();     // producers' lsum_lds writes now visible

        // ---- epilogue: out = gamma*acc/lsum + x ----
        const float g = gamma[0];
#pragma unroll
        for (int rq = 0; rq < 4; ++rq) {
            const int rbase = 8 * rq + 4 * l5;
#define STORE_QB(ACC, QB)                                                      \
            {                                                                  \
                f32x4 ls = *(const f32x4*)&lsum_lds[32 * (QB) + rbase];        \
                f32x4 gi;                                                      \
                gi[0] = g / ls[0]; gi[1] = g / ls[1];                          \
                gi[2] = g / ls[2]; gi[3] = g / ls[3];                          \
                size_t off = bx_base + (size_t)ch * 4096 + s0 + 32 * (QB) + rbase; \
                f32x4 xv = *(const f32x4*)(x + off);                           \
                f32x4 o;                                                       \
                o[0] = gi[0] * (ACC)[4 * rq + 0] + xv[0];                      \
                o[1] = gi[1] * (ACC)[4 * rq + 1] + xv[1];                      \
                o[2] = gi[2] * (ACC)[4 * rq + 2] + xv[2];                      \
                o[3] = gi[3] * (ACC)[4 * rq + 3] + xv[3];                      \
                *(f32x4*)(out + off) = o;                                      \
            }
            STORE_QB(acc0, 0)
            STORE_QB(acc1, 1)
            STORE_QB(acc2, 2)
            STORE_QB(acc3, 3)
#undef STORE_QB
        }
    }
}

// ---------------------------------------------------------------------------
extern "C" void kernel_launch(void* const* d_in, const int* in_sizes, int n_in,
                              void* d_out, int out_size, void* d_ws, size_t ws_size,
                              hipStream_t stream) {
    const float* x     = (const float*)d_in[0];
    const float* wqk   = (const float*)d_in[1];
    const float* wv    = (const float*)d_in[2];
    const float* gamma = (const float*)d_in[3];
    float* out = (float*)d_out;

    char* ws = (char*)d_ws;
    unsigned short* W     = (unsigned short*)(ws);                      // 160 KiB
    unsigned short* qkT   = (unsigned short*)(ws + 163840);             // 4 MiB
    unsigned short* xT    = (unsigned short*)(ws + 4358144);            // 16 MiB (-> vfrag)
    unsigned short* vbuf  = (unsigned short*)(ws + 21135360);           // 16 MiB
    unsigned short* kfrag = (unsigned short*)(ws + 37912576);           // 2 MiB
    unsigned short* vfrag = xT;   // reuse xT region (dead after proj)

    hipLaunchKernelGGL(prep_w_kernel,    dim3(320),  dim3(256), 0, stream, wqk, wv, W);
    hipLaunchKernelGGL(transpose_kernel, dim3(2048), dim3(256), 0, stream, x, xT);
    hipLaunchKernelGGL(proj_kernel,      dim3(512),  dim3(256), 0, stream, W, xT, qkT, vbuf);
    hipLaunchKernelGGL(repack_v_kernel,  dim3(4096), dim3(256), 0, stream, vbuf, vfrag);
    hipLaunchKernelGGL(repack_k_kernel,  dim3(512),  dim3(256), 0, stream, qkT, kfrag);
    hipLaunchKernelGGL(attn_kernel,      dim3(256),  dim3(768), 0, stream, qkT, kfrag, vfrag, x, gamma, out);
}

// Round 17
// 143.834 us; speedup vs baseline: 3.5732x; 1.0155x over previous
//
#include <hip/hip_runtime.h>

typedef __attribute__((ext_vector_type(4)))  float f32x4;
typedef __attribute__((ext_vector_type(16))) float f32x16;
typedef __attribute__((ext_vector_type(8)))  short short8;
typedef __attribute__((ext_vector_type(4)))  unsigned short u16x4;
typedef __attribute__((ext_vector_type(4)))  unsigned int u32x4;
typedef __attribute__((ext_vector_type(2)))  unsigned int u32x2;

// float -> bf16, round-to-nearest-even
static __device__ __forceinline__ unsigned short f2bf(float f) {
    unsigned int u = __float_as_uint(f);
    unsigned int r = (u + 0x7FFFu + ((u >> 16) & 1u)) >> 16;
    return (unsigned short)r;
}

#if __has_builtin(__builtin_amdgcn_exp2f)
#define EXP2(x) __builtin_amdgcn_exp2f(x)
#else
#define EXP2(x) exp2f(x)
#endif

static __device__ __forceinline__ u32x2 swap32v(unsigned int a, unsigned int b) {
#if __has_builtin(__builtin_amdgcn_permlane32_swap)
    return __builtin_amdgcn_permlane32_swap(a, b, false, false);
#else
    asm("v_permlane32_swap_b32 %0, %1" : "+v"(a), "+v"(b));
    u32x2 r; r[0] = a; r[1] = b; return r;
#endif
}

// lgkm-drain + raw barrier (vmcnt NOT drained: K/V prefetches stay in flight)
static __device__ __forceinline__ void block_sync_lds() {
    asm volatile("s_waitcnt lgkmcnt(0)" ::: "memory");
    __builtin_amdgcn_s_barrier();
    asm volatile("" ::: "memory");
}

// 32^-0.5 * log2(e)
#define SCALE2Q 0.25503487756f

// ---------------------------------------------------------------------------
__global__ void prep_w_kernel(const float* __restrict__ wqk,
                              const float* __restrict__ wv,
                              unsigned short* __restrict__ W) {
    int idx = blockIdx.x * 256 + threadIdx.x;
    int o = idx >> 8, c = idx & 255;
    float v;
    if (o < 64) { v = wqk[o * 256 + c]; if (o < 32) v *= SCALE2Q; }
    else        { v = wv[(o - 64) * 256 + c]; }
    W[idx] = f2bf(v);
}

// ---------------------------------------------------------------------------
__global__ __launch_bounds__(256) void transpose_kernel(
        const float* __restrict__ x, unsigned short* __restrict__ xT) {
    __shared__ unsigned short tile[64][66];
    int b = blockIdx.x & 7;
    int rem = blockIdx.x >> 3;
    int ct = rem >> 6, st = rem & 63;
    int s0 = st * 64, c0 = ct * 64;
    int tid = threadIdx.x;
    int ss = tid & 63, cq = tid >> 6;
#pragma unroll
    for (int p = 0; p < 16; ++p) {
        int cc = p * 4 + cq;
        float v = x[(size_t)(b * 256 + c0 + cc) * 4096 + s0 + ss];
        tile[ss][cc] = f2bf(v);
    }
    __syncthreads();
#pragma unroll
    for (int p = 0; p < 8; ++p) {
        int idx = p * 256 + tid;
        int sr = idx >> 5, jj = idx & 31;
        unsigned int val = *(const unsigned int*)&tile[sr][jj * 2];
        *(unsigned int*)(xT + (size_t)(b * 4096 + s0 + sr) * 256 + c0 + jj * 2) = val;
    }
}

// ---------------------------------------------------------------------------
__global__ __launch_bounds__(256) void proj_kernel(
        const unsigned short* __restrict__ W,    // [320][256]
        const unsigned short* __restrict__ xT,   // [8][4096][256]
        unsigned short* __restrict__ qkT,        // [8][4096][64]
        unsigned short* __restrict__ vbuf) {     // [8][256][4096]
    const int b  = blockIdx.x & 7;
    const int sb = blockIdx.x >> 3;
    const int s0 = sb * 64;
    const int tid = threadIdx.x;
    const int w = tid >> 6, l = tid & 63;
    const int lg = l >> 4, ll = l & 15;
    const size_t xbase = (size_t)b * 4096 * 256;

    f32x4 acc[5][4];
#pragma unroll
    for (int ot = 0; ot < 5; ++ot)
#pragma unroll
        for (int st = 0; st < 4; ++st) acc[ot][st] = (f32x4)0.0f;

    for (int k0 = 0; k0 < 256; k0 += 32) {
        short8 bf[4], af[5];
#pragma unroll
        for (int st = 0; st < 4; ++st)
            bf[st] = *(const short8*)(xT + xbase + (size_t)(s0 + st * 16 + ll) * 256 + k0 + lg * 8);
#pragma unroll
        for (int ot = 0; ot < 5; ++ot)
            af[ot] = *(const short8*)(W + (size_t)(80 * w + ot * 16 + ll) * 256 + k0 + lg * 8);
#pragma unroll
        for (int ot = 0; ot < 5; ++ot)
#pragma unroll
            for (int st = 0; st < 4; ++st)
                acc[ot][st] = __builtin_amdgcn_mfma_f32_16x16x32_bf16(af[ot], bf[st], acc[ot][st], 0, 0, 0);
    }
#pragma unroll
    for (int ot = 0; ot < 5; ++ot) {
        int o0 = 80 * w + ot * 16 + lg * 4;
#pragma unroll
        for (int st = 0; st < 4; ++st) {
            int s = s0 + st * 16 + ll;
            if (o0 < 64) {
                u16x4 pk;
#pragma unroll
                for (int i = 0; i < 4; ++i) pk[i] = f2bf(acc[ot][st][i]);
                *(u16x4*)(qkT + (size_t)b * 4096 * 64 + (size_t)s * 64 + o0) = pk;
            } else {
#pragma unroll
                for (int i = 0; i < 4; ++i)
                    vbuf[(size_t)b * 256 * 4096 + (size_t)(o0 - 64 + i) * 4096 + s] = f2bf(acc[ot][st][i]);
            }
        }
    }
}

// ---------------------------------------------------------------------------
__global__ __launch_bounds__(256) void repack_v_kernel(
        const unsigned short* __restrict__ vbuf,   // [8][256][4096]
        unsigned short* __restrict__ vfrag) {      // [8][8][256][64][8]
    int idx = blockIdx.x * 256 + threadIdx.x;
    int l    = idx & 63;
    int kf16 = (idx >> 6) & 255;
    int ct4  = (idx >> 14) & 7;
    int b    = idx >> 17;
    int l31 = l & 31, l5 = l >> 5;
    short8 v = *(const short8*)(vbuf + (size_t)b * 256 * 4096
                                + (size_t)(32 * ct4 + l31) * 4096
                                + 16 * kf16 + 8 * l5);
    *(short8*)(vfrag + (size_t)idx * 8) = v;
}

// ---------------------------------------------------------------------------
__global__ __launch_bounds__(256) void repack_k_kernel(
        const unsigned short* __restrict__ qkT,    // [8][4096][64]
        unsigned short* __restrict__ kfrag) {      // [8][128][2][64][8]
    int idx = blockIdx.x * 256 + threadIdx.x;
    int l  = idx & 63;
    int h  = (idx >> 6) & 1;
    int t2 = (idx >> 7) & 127;
    int b  = idx >> 14;
    int l31 = l & 31, l5 = l >> 5;
    short8 v = *(const short8*)(qkT + (size_t)b * 4096 * 64
                                + (size_t)(32 * t2 + l31) * 64
                                + 32 + 16 * h + 8 * l5);
    *(short8*)(kfrag + (size_t)idx * 8) = v;
}

// ---------------------------------------------------------------------------
// Kernel 4: attention, P/C wave split, 4+4 waves (512 thr), 1 block/CU.
// Waves 0-3 (producers, 32 q each): coalesced kfrag -> swapped QK ->
// exp2 -> cvt_pk+permlane -> 4x ds_write_b128 into dbuf p_lds.
// Waves 4-7 (consumers, 64 ch each): per phase 16x ds_read_b128 (P for all
// 4 q-blocks) + 32 PV MFMA (4 qb x 2 ct x 4 ks) + rolling vfrag loads.
// Halved P-read LDS traffic vs 8-consumer variant (each consumer covers
// 2x channels). One lgkm-only barrier per tile, 1-tile P/C skew.
// ---------------------------------------------------------------------------
__global__ __launch_bounds__(512, 2) void attn_kernel(
        const unsigned short* __restrict__ qkT,   // [8][4096][64] (q|k)
        const unsigned short* __restrict__ kfrag, // [8][128][2][64][8]
        const unsigned short* __restrict__ vfrag, // [8][8][256][64][8]
        const float* __restrict__ x,              // [8][256][4096]
        const float* __restrict__ gamma,
        float* __restrict__ out) {
    __shared__ unsigned short p_lds[2][4][4][64][8];  // 32 KiB [buf][qb][ks][lane][8]
    __shared__ float lsum_lds[128];

    const int b   = blockIdx.x & 7;          // batch == XCD (L2 pinning)
    const int sb  = blockIdx.x >> 3;         // 0..31
    const int s0  = sb * 128;
    const int w   = threadIdx.x >> 6;        // 0..7
    const int l   = threadIdx.x & 63;
    const int l5  = l >> 5, l31 = l & 31;

    const size_t qk_base = (size_t)b * 4096 * 64;
    const size_t bx_base = (size_t)b * 256 * 4096;

    if (w < 4) {
        // ================= PRODUCER: q-rows [s0+32w, +32) ===================
        const unsigned short* qrow = qkT + qk_base + (size_t)(s0 + 32 * w + l31) * 64;
        const short8 qf0 = *(const short8*)(qrow + 8 * l5);
        const short8 qf1 = *(const short8*)(qrow + 16 + 8 * l5);
        const unsigned short* kfp = kfrag + (size_t)b * 128 * 2 * 512 + 8 * l;
        const f32x16 z16 = (f32x16)0.0f;
        float psum = 0.f;

        short8 kf00 = *(const short8*)(kfp + 0 * 512);
        short8 kf01 = *(const short8*)(kfp + 1 * 512);
        short8 kf10 = *(const short8*)(kfp + 2 * 512);
        short8 kf11 = *(const short8*)(kfp + 3 * 512);

#define EXPPACK(DD, PLO, PHI)                                                  \
    {                                                                          \
        float e0 = EXP2((DD)[0]),   e1 = EXP2((DD)[1]);                        \
        float e2 = EXP2((DD)[2]),   e3 = EXP2((DD)[3]);                        \
        float e4 = EXP2((DD)[4]),   e5 = EXP2((DD)[5]);                        \
        float e6 = EXP2((DD)[6]),   e7 = EXP2((DD)[7]);                        \
        float e8 = EXP2((DD)[8]),   e9 = EXP2((DD)[9]);                        \
        float e10 = EXP2((DD)[10]), e11 = EXP2((DD)[11]);                      \
        float e12 = EXP2((DD)[12]), e13 = EXP2((DD)[13]);                      \
        float e14 = EXP2((DD)[14]), e15 = EXP2((DD)[15]);                      \
        psum += (((e0 + e1) + (e2 + e3)) + ((e4 + e5) + (e6 + e7)))            \
              + (((e8 + e9) + (e10 + e11)) + ((e12 + e13) + (e14 + e15)));     \
        unsigned int c0, c1, c2, c3;                                           \
        asm("v_cvt_pk_bf16_f32 %0, %1, %2" : "=v"(c0) : "v"(e0), "v"(e1));     \
        asm("v_cvt_pk_bf16_f32 %0, %1, %2" : "=v"(c1) : "v"(e2), "v"(e3));     \
        asm("v_cvt_pk_bf16_f32 %0, %1, %2" : "=v"(c2) : "v"(e4), "v"(e5));     \
        asm("v_cvt_pk_bf16_f32 %0, %1, %2" : "=v"(c3) : "v"(e6), "v"(e7));     \
        u32x2 s0_ = swap32v(c0, c2);                                           \
        u32x2 s1_ = swap32v(c1, c3);                                           \
        u32x4 lo_; lo_[0] = s0_[0]; lo_[1] = s1_[0]; lo_[2] = s0_[1]; lo_[3] = s1_[1]; \
        PLO = __builtin_bit_cast(short8, lo_);                                 \
        unsigned int d0, d1, d2, d3;                                           \
        asm("v_cvt_pk_bf16_f32 %0, %1, %2" : "=v"(d0) : "v"(e8), "v"(e9));     \
        asm("v_cvt_pk_bf16_f32 %0, %1, %2" : "=v"(d1) : "v"(e10), "v"(e11));   \
        asm("v_cvt_pk_bf16_f32 %0, %1, %2" : "=v"(d2) : "v"(e12), "v"(e13));   \
        u32x2 s2_ = swap32v(d0, d2);                                           \
        asm("v_cvt_pk_bf16_f32 %0, %1, %2" : "=v"(d3) : "v"(e14), "v"(e15));   \
        u32x2 s3_ = swap32v(d1, d3);                                           \
        u32x4 hi_; hi_[0] = s2_[0]; hi_[1] = s3_[0]; hi_[2] = s2_[1]; hi_[3] = s3_[1]; \
        PHI = __builtin_bit_cast(short8, hi_);                                 \
    }

#define PRODUCE(T)                                                             \
    {                                                                          \
        const int tn_ = ((T) + 1) & 63;                                        \
        const int pb_ = (T) & 1;                                               \
        f32x16 dd0 = __builtin_amdgcn_mfma_f32_32x32x16_bf16(kf00, qf0, z16, 0, 0, 0); \
        dd0 = __builtin_amdgcn_mfma_f32_32x32x16_bf16(kf01, qf1, dd0, 0, 0, 0);\
        f32x16 dd1 = __builtin_amdgcn_mfma_f32_32x32x16_bf16(kf10, qf0, z16, 0, 0, 0); \
        dd1 = __builtin_amdgcn_mfma_f32_32x32x16_bf16(kf11, qf1, dd1, 0, 0, 0);\
        kf00 = *(const short8*)(kfp + (size_t)(4 * tn_ + 0) * 512);            \
        kf01 = *(const short8*)(kfp + (size_t)(4 * tn_ + 1) * 512);            \
        kf10 = *(const short8*)(kfp + (size_t)(4 * tn_ + 2) * 512);            \
        kf11 = *(const short8*)(kfp + (size_t)(4 * tn_ + 3) * 512);            \
        short8 pa0, pa1, pa2, pa3;                                             \
        EXPPACK(dd0, pa0, pa1)                                                 \
        EXPPACK(dd1, pa2, pa3)                                                 \
        *(short8*)&p_lds[pb_][w][0][l][0] = pa0;                               \
        *(short8*)&p_lds[pb_][w][1][l][0] = pa1;                               \
        *(short8*)&p_lds[pb_][w][2][l][0] = pa2;                               \
        *(short8*)&p_lds[pb_][w][3][l][0] = pa3;                               \
    }

        PRODUCE(0)
        for (int t = 1; t < 64; ++t) {
            block_sync_lds();
            PRODUCE(t)
        }
        block_sync_lds();
#undef PRODUCE
#undef EXPPACK

        psum += __shfl_xor(psum, 32);
        if (l5 == 0) lsum_lds[32 * w + l31] = psum;
        __syncthreads();
    } else {
        // ================= CONSUMER: channels [64(w-4), +64) ================
        const int cw = w - 4;                 // 0..3
        const int ct0 = 2 * cw, ct1 = 2 * cw + 1;
        const unsigned short* vfp0 = vfrag + ((size_t)(b * 8 + ct0) * 256) * 512 + 8 * l;
        const unsigned short* vfp1 = vfrag + ((size_t)(b * 8 + ct1) * 256) * 512 + 8 * l;

        // acc[qb][ct]: 8 x f32x16 = 128 AGPR
        f32x16 a00 = (f32x16)0.0f, a10 = (f32x16)0.0f;
        f32x16 a20 = (f32x16)0.0f, a30 = (f32x16)0.0f;
        f32x16 a01 = (f32x16)0.0f, a11 = (f32x16)0.0f;
        f32x16 a21 = (f32x16)0.0f, a31 = (f32x16)0.0f;
        // vf rolling: slot A (even ks), slot B (odd ks), per ct
        short8 vA0 = *(const short8*)(vfp0 + 0 * 512);
        short8 vA1 = *(const short8*)(vfp1 + 0 * 512);
        short8 vB0 = *(const short8*)(vfp0 + 1 * 512);
        short8 vB1 = *(const short8*)(vfp1 + 1 * 512);

#define CKS(KS, V0, V1)                                                        \
        {                                                                      \
            short8 p0 = *(const short8*)&p_lds[pb][0][KS][l][0];               \
            short8 p1 = *(const short8*)&p_lds[pb][1][KS][l][0];               \
            short8 p2 = *(const short8*)&p_lds[pb][2][KS][l][0];               \
            short8 p3 = *(const short8*)&p_lds[pb][3][KS][l][0];               \
            a00 = __builtin_amdgcn_mfma_f32_32x32x16_bf16(p0, V0, a00, 0, 0, 0); \
            a10 = __builtin_amdgcn_mfma_f32_32x32x16_bf16(p1, V0, a10, 0, 0, 0); \
            a20 = __builtin_amdgcn_mfma_f32_32x32x16_bf16(p2, V0, a20, 0, 0, 0); \
            a30 = __builtin_amdgcn_mfma_f32_32x32x16_bf16(p3, V0, a30, 0, 0, 0); \
            a01 = __builtin_amdgcn_mfma_f32_32x32x16_bf16(p0, V1, a01, 0, 0, 0); \
            a11 = __builtin_amdgcn_mfma_f32_32x32x16_bf16(p1, V1, a11, 0, 0, 0); \
            a21 = __builtin_amdgcn_mfma_f32_32x32x16_bf16(p2, V1, a21, 0, 0, 0); \
            a31 = __builtin_amdgcn_mfma_f32_32x32x16_bf16(p3, V1, a31, 0, 0, 0); \
        }

        for (int t = 0; t < 64; ++t) {
            block_sync_lds();
            const int pb = t & 1;
            const int tn = (t + 1) & 63;
            CKS(0, vA0, vA1)
            vA0 = *(const short8*)(vfp0 + (size_t)(4 * t + 2) * 512);
            vA1 = *(const short8*)(vfp1 + (size_t)(4 * t + 2) * 512);
            CKS(1, vB0, vB1)
            vB0 = *(const short8*)(vfp0 + (size_t)(4 * t + 3) * 512);
            vB1 = *(const short8*)(vfp1 + (size_t)(4 * t + 3) * 512);
            CKS(2, vA0, vA1)
            vA0 = *(const short8*)(vfp0 + (size_t)(4 * tn + 0) * 512);
            vA1 = *(const short8*)(vfp1 + (size_t)(4 * tn + 0) * 512);
            CKS(3, vB0, vB1)
            vB0 = *(const short8*)(vfp0 + (size_t)(4 * tn + 1) * 512);
            vB1 = *(const short8*)(vfp1 + (size_t)(4 * tn + 1) * 512);
        }
#undef CKS
        __syncthreads();     // producers' lsum_lds writes now visible

        // ---- epilogue: out = gamma*acc/lsum + x ----
        const float g = gamma[0];
#pragma unroll
        for (int rq = 0; rq < 4; ++rq) {
            const int rbase = 8 * rq + 4 * l5;
#define STORE_QB(ACC, QB, CT)                                                  \
            {                                                                  \
                f32x4 ls = *(const f32x4*)&lsum_lds[32 * (QB) + rbase];        \
                f32x4 gi;                                                      \
                gi[0] = g / ls[0]; gi[1] = g / ls[1];                          \
                gi[2] = g / ls[2]; gi[3] = g / ls[3];                          \
                size_t off = bx_base + (size_t)(32 * (CT) + l31) * 4096 + s0 + 32 * (QB) + rbase; \
                f32x4 xv = *(const f32x4*)(x + off);                           \
                f32x4 o;                                                       \
                o[0] = gi[0] * (ACC)[4 * rq + 0] + xv[0];                      \
                o[1] = gi[1] * (ACC)[4 * rq + 1] + xv[1];                      \
                o[2] = gi[2] * (ACC)[4 * rq + 2] + xv[2];                      \
                o[3] = gi[3] * (ACC)[4 * rq + 3] + xv[3];                      \
                *(f32x4*)(out + off) = o;                                      \
            }
            STORE_QB(a00, 0, ct0)
            STORE_QB(a10, 1, ct0)
            STORE_QB(a20, 2, ct0)
            STORE_QB(a30, 3, ct0)
            STORE_QB(a01, 0, ct1)
            STORE_QB(a11, 1, ct1)
            STORE_QB(a21, 2, ct1)
            STORE_QB(a31, 3, ct1)
#undef STORE_QB
        }
    }
}

// ---------------------------------------------------------------------------
extern "C" void kernel_launch(void* const* d_in, const int* in_sizes, int n_in,
                              void* d_out, int out_size, void* d_ws, size_t ws_size,
                              hipStream_t stream) {
    const float* x     = (const float*)d_in[0];
    const float* wqk   = (const float*)d_in[1];
    const float* wv    = (const float*)d_in[2];
    const float* gamma = (const float*)d_in[3];
    float* out = (float*)d_out;

    char* ws = (char*)d_ws;
    unsigned short* W     = (unsigned short*)(ws);                      // 160 KiB
    unsigned short* qkT   = (unsigned short*)(ws + 163840);             // 4 MiB
    unsigned short* xT    = (unsigned short*)(ws + 4358144);            // 16 MiB (-> vfrag)
    unsigned short* vbuf  = (unsigned short*)(ws + 21135360);           // 16 MiB
    unsigned short* kfrag = (unsigned short*)(ws + 37912576);           // 2 MiB
    unsigned short* vfrag = xT;   // reuse xT region (dead after proj)

    hipLaunchKernelGGL(prep_w_kernel,    dim3(320),  dim3(256), 0, stream, wqk, wv, W);
    hipLaunchKernelGGL(transpose_kernel, dim3(2048), dim3(256), 0, stream, x, xT);
    hipLaunchKernelGGL(proj_kernel,      dim3(512),  dim3(256), 0, stream, W, xT, qkT, vbuf);
    hipLaunchKernelGGL(repack_v_kernel,  dim3(4096), dim3(256), 0, stream, vbuf, vfrag);
    hipLaunchKernelGGL(repack_k_kernel,  dim3(512),  dim3(256), 0, stream, qkT, kfrag);
    hipLaunchKernelGGL(attn_kernel,      dim3(256),  dim3(512), 0, stream, qkT, kfrag, vfrag, x, gamma, out);
}